// Round 7
// baseline (313.076 us; speedup 1.0000x reference)
//
#include <hip/hip_runtime.h>
#include <math.h>

#define BB 128
#define MM 35
#define PSZ 224
#define PP (PSZ*PSZ)          // 50176
#define SIGN_PENALTY 10.0f
#define RECON_WEIGHT 0.4f
#define DEFOCUS_RAD 1.0f
#define EPS_F 1e-8f
#define INV2PI 0.15915494309189535f

// CT: 224 = 14*16. n = 14*n2 + n1; k = 16*k1 + k2full.
// Inner 16-pt DFT: output-side radix-4, STREAMED from LDS (src) to LDS (dst):
//   for k2 in 0..3: P_j = sum_m x[4m+j]*W4^{m*k2} (trivial rots, streamed),
//   S_j = P_j*W16^{j*k2}, X16[k2+4r] = DFT4(S)_r.  Max ~20 floats live.
// Double-buffered xs->ys (streamed radix can't be in-place).
// Outer 14-pt: 2x7 split from y[14] registers (R4-proven liveness).

// ws layout (floats):
//   [1] z_loss  [2..8] mask^2 partials (7)  [10] recon atomic sum  [11] counter
//   [2048 ..) phase [B][P][P]
//   [T_OFF ..) T [2][B][P][P] packed bf16x2
#define WS_PHASE_OFF    2048
#define WS_T_OFF        (WS_PHASE_OFF + BB*PP)
#define NBLK2           (14*BB*2)
#define SX1 226           // stage1 LDS row stride (dwords)
#define SX2 17            // stage2 LDS col-tile stride (dwords)

static constexpr float W16R[16] = {
    1.0f, 0.9238795325f, 0.7071067812f, 0.3826834324f, 0.0f,
    -0.3826834324f, -0.7071067812f, -0.9238795325f, -1.0f,
    -0.9238795325f, -0.7071067812f, -0.3826834324f, 0.0f,
    0.3826834324f, 0.7071067812f, 0.9238795325f};
static constexpr float W16I[16] = {
    0.0f, -0.3826834324f, -0.7071067812f, -0.9238795325f, -1.0f,
    -0.9238795325f, -0.7071067812f, -0.3826834324f, 0.0f,
    0.3826834324f, 0.7071067812f, 0.9238795325f, 1.0f,
    0.9238795325f, 0.7071067812f, 0.3826834324f};
static constexpr float W7R[7] = {
    1.0f, 0.6234898019f, -0.2225209340f, -0.9009688679f,
    -0.9009688679f, -0.2225209340f, 0.6234898019f};
static constexpr float W7I[7] = {
    0.0f, -0.7818314825f, -0.9749279122f, -0.4338837391f,
    0.4338837391f, 0.9749279122f, 0.7818314825f};
static constexpr float W14R[7] = {
    1.0f, 0.9009688679f, 0.6234898019f, 0.2225209340f, -0.2225209340f,
    -0.6234898019f, -0.9009688679f};
static constexpr float W14I[7] = {
    0.0f, -0.4338837391f, -0.7818314825f, -0.9749279122f, -0.9749279122f,
    -0.7818314825f, -0.4338837391f};

__device__ __forceinline__ float lincoord(int i) {
    return -1.0f + 2.0f * (float)i / (float)(PSZ - 1);
}
__device__ __forceinline__ void fast_sincos(float x, float* s, float* c) {
    float rv = x * INV2PI;
    rv -= floorf(rv);
    *s = __builtin_amdgcn_sinf(rv);
    *c = __builtin_amdgcn_cosf(rv);
}
__device__ __forceinline__ unsigned pack_bf2(float a, float b) {
    return ((__float_as_uint(a) + 0x8000u) >> 16) |
           ((__float_as_uint(b) + 0x8000u) & 0xffff0000u);
}
__device__ __forceinline__ float2 unpack_bf2(unsigned v) {
    return make_float2(__uint_as_float(v << 16), __uint_as_float(v & 0xffff0000u));
}
__device__ __forceinline__ float2 cmul(float2 a, float2 b) {
    return make_float2(fmaf(a.x, b.x, -a.y * b.y), fmaf(a.x, b.y, a.y * b.x));
}
__device__ __forceinline__ float2 cmulc(float2 a, float wr, float wi) {
    return make_float2(fmaf(a.x, wr, -a.y * wi), fmaf(a.x, wi, a.y * wr));
}
__device__ __forceinline__ float2 cadd(float2 a, float2 b) {
    return make_float2(a.x + b.x, a.y + b.y);
}
__device__ __forceinline__ float2 csub(float2 a, float2 b) {
    return make_float2(a.x - b.x, a.y - b.y);
}
// rotate by W4^P = (-i)^P — compile-time, free
template<int P> __device__ __forceinline__ float2 rotc(float2 v);
template<> __device__ __forceinline__ float2 rotc<0>(float2 v) { return v; }
template<> __device__ __forceinline__ float2 rotc<1>(float2 v) { return make_float2(v.y, -v.x); }
template<> __device__ __forceinline__ float2 rotc<2>(float2 v) { return make_float2(-v.x, -v.y); }
template<> __device__ __forceinline__ float2 rotc<3>(float2 v) { return make_float2(-v.y, v.x); }

// multiply-free forward DFT-4: o_r = sum_j in_j * W4^{j*r}
__device__ __forceinline__ void dft4(float2 a, float2 b, float2 c, float2 d,
                                     float2* o0, float2* o1, float2* o2, float2* o3) {
    float t0r = a.x + c.x, t0i = a.y + c.y;
    float t1r = b.x + d.x, t1i = b.y + d.y;
    float t2r = a.x - c.x, t2i = a.y - c.y;
    float t3r = b.x - d.x, t3i = b.y - d.y;
    *o0 = make_float2(t0r + t1r, t0i + t1i);
    *o2 = make_float2(t0r - t1r, t0i - t1i);
    *o1 = make_float2(t2r + t3i, t2i - t3r);
    *o3 = make_float2(t2r - t3i, t2i + t3r);
}

// one radix-4 output group: o_r = X16[K2 + 4r], streamed from LDS.
// addr of input n2: a + n2*st  (a = base + n1*mul, st = 14*mul)
template<int K2>
__device__ __forceinline__ void inner_group(const unsigned* __restrict__ lds, int a, int st,
                                            float2& o0, float2& o1, float2& o2, float2& o3) {
    float2 x0, x1, x2, x3, P0, P1, P2, P3;
    x0 = unpack_bf2(lds[a]);           x1 = unpack_bf2(lds[a + 4 * st]);
    x2 = unpack_bf2(lds[a + 8 * st]);  x3 = unpack_bf2(lds[a + 12 * st]);
    P0 = cadd(cadd(x0, rotc<(1*K2)&3>(x1)), cadd(rotc<(2*K2)&3>(x2), rotc<(3*K2)&3>(x3)));
    x0 = unpack_bf2(lds[a + 1 * st]);  x1 = unpack_bf2(lds[a + 5 * st]);
    x2 = unpack_bf2(lds[a + 9 * st]);  x3 = unpack_bf2(lds[a + 13 * st]);
    P1 = cadd(cadd(x0, rotc<(1*K2)&3>(x1)), cadd(rotc<(2*K2)&3>(x2), rotc<(3*K2)&3>(x3)));
    if constexpr (K2 != 0) P1 = cmulc(P1, W16R[(1*K2)&15], W16I[(1*K2)&15]);
    x0 = unpack_bf2(lds[a + 2 * st]);  x1 = unpack_bf2(lds[a + 6 * st]);
    x2 = unpack_bf2(lds[a + 10 * st]); x3 = unpack_bf2(lds[a + 14 * st]);
    P2 = cadd(cadd(x0, rotc<(1*K2)&3>(x1)), cadd(rotc<(2*K2)&3>(x2), rotc<(3*K2)&3>(x3)));
    if constexpr (K2 != 0) P2 = cmulc(P2, W16R[(2*K2)&15], W16I[(2*K2)&15]);
    x0 = unpack_bf2(lds[a + 3 * st]);  x1 = unpack_bf2(lds[a + 7 * st]);
    x2 = unpack_bf2(lds[a + 11 * st]); x3 = unpack_bf2(lds[a + 15 * st]);
    P3 = cadd(cadd(x0, rotc<(1*K2)&3>(x1)), cadd(rotc<(2*K2)&3>(x2), rotc<(3*K2)&3>(x3)));
    if constexpr (K2 != 0) P3 = cmulc(P3, W16R[(3*K2)&15], W16I[(3*K2)&15]);
    dft4(P0, P1, P2, P3, &o0, &o1, &o2, &o3);
}

// full inner 16-pt DFT + inter-stage twiddle W224^{n1*k}, src->dst (both LDS).
// sa/da: base addr (includes n1*mul); st = 14*mul; dst slot k at da + k*st.
__device__ __forceinline__ void inner224(const unsigned* __restrict__ src,
                                         unsigned* __restrict__ dst,
                                         int sa, int da, int st, int n1) {
    float2 u1, u4, cur, Tg, o0, o1, o2, o3, z;
    { float rv = (float)n1 * (-1.0f / 224.0f); rv -= floorf(rv);
      u1 = make_float2(__builtin_amdgcn_cosf(rv), __builtin_amdgcn_sinf(rv)); }
    { float rv = (float)n1 * (-1.0f / 56.0f); rv -= floorf(rv);
      u4 = make_float2(__builtin_amdgcn_cosf(rv), __builtin_amdgcn_sinf(rv)); }
    // group 0: k = 0,4,8,12 (base twiddle = 1)
    inner_group<0>(src, sa, st, o0, o1, o2, o3);
    dst[da]          = pack_bf2(o0.x, o0.y);
    cur = u4;            z = cmul(o1, cur); dst[da + 4 * st]  = pack_bf2(z.x, z.y);
    cur = cmul(cur, u4); z = cmul(o2, cur); dst[da + 8 * st]  = pack_bf2(z.x, z.y);
    cur = cmul(cur, u4); z = cmul(o3, cur); dst[da + 12 * st] = pack_bf2(z.x, z.y);
    // group 1: k = 1,5,9,13 (base twiddle u1)
    inner_group<1>(src, sa, st, o0, o1, o2, o3);
    Tg = u1;
    z = cmul(o0, Tg);    dst[da + 1 * st]  = pack_bf2(z.x, z.y);
    cur = cmul(Tg, u4);  z = cmul(o1, cur); dst[da + 5 * st]  = pack_bf2(z.x, z.y);
    cur = cmul(cur, u4); z = cmul(o2, cur); dst[da + 9 * st]  = pack_bf2(z.x, z.y);
    cur = cmul(cur, u4); z = cmul(o3, cur); dst[da + 13 * st] = pack_bf2(z.x, z.y);
    // group 2: k = 2,6,10,14
    inner_group<2>(src, sa, st, o0, o1, o2, o3);
    Tg = cmul(Tg, u1);
    z = cmul(o0, Tg);    dst[da + 2 * st]  = pack_bf2(z.x, z.y);
    cur = cmul(Tg, u4);  z = cmul(o1, cur); dst[da + 6 * st]  = pack_bf2(z.x, z.y);
    cur = cmul(cur, u4); z = cmul(o2, cur); dst[da + 10 * st] = pack_bf2(z.x, z.y);
    cur = cmul(cur, u4); z = cmul(o3, cur); dst[da + 14 * st] = pack_bf2(z.x, z.y);
    // group 3: k = 3,7,11,15
    inner_group<3>(src, sa, st, o0, o1, o2, o3);
    Tg = cmul(Tg, u1);
    z = cmul(o0, Tg);    dst[da + 3 * st]  = pack_bf2(z.x, z.y);
    cur = cmul(Tg, u4);  z = cmul(o1, cur); dst[da + 7 * st]  = pack_bf2(z.x, z.y);
    cur = cmul(cur, u4); z = cmul(o2, cur); dst[da + 11 * st] = pack_bf2(z.x, z.y);
    cur = cmul(cur, u4); z = cmul(o3, cur); dst[da + 15 * st] = pack_bf2(z.x, z.y);
}

// ---------------- k_phase: grid (197, 8). x<196: phase GEMM. x==196: small work.
__global__ __launch_bounds__(256) void k_phase(const float* __restrict__ pred,
                                               const float* __restrict__ target,
                                               const float* __restrict__ zern,
                                               const float* __restrict__ mask,
                                               float* __restrict__ phase,
                                               float* __restrict__ ws) {
    __shared__ float pl[16 * MM];
    __shared__ float red[256];
    int t = threadIdx.x;
    if (blockIdx.x == 196) {
        int y = blockIdx.y;
        float s = 0.f;
        if (y == 0) {
            if (t == 0) { ws[10] = 0.f; ((unsigned*)ws)[11] = 0u; }
            for (int i = t; i < BB * MM; i += 256) {
                float p = pred[i], tg = target[i];
                float dd = p - tg;
                float w = (p * tg < 0.f) ? SIGN_PENALTY : 1.f;
                s = fmaf(dd * dd, w, s);
            }
        } else {
            const float4* m4 = (const float4*)(mask + (y - 1) * (PP / 7));
            for (int i = t; i < PP / 28; i += 256) {
                float4 v = m4[i];
                s = fmaf(v.x, v.x, s); s = fmaf(v.y, v.y, s);
                s = fmaf(v.z, v.z, s); s = fmaf(v.w, v.w, s);
            }
        }
        red[t] = s;
        __syncthreads();
        for (int st = 128; st > 0; st >>= 1) {
            if (t < st) red[t] += red[t + st];
            __syncthreads();
        }
        if (t == 0) {
            if (y == 0) ws[1] = red[0] / (float)(BB * MM);
            else        ws[1 + y] = red[0];
        }
        return;
    }
    int bg = blockIdx.y;
    for (int i = t; i < 16 * MM; i += 256) {
        int j = i / MM, m = i % MM;
        pl[i] = pred[(bg * 16 + j) * MM + m];
    }
    __syncthreads();
    int pix = blockIdx.x * 256 + t;
    float acc[16];
#pragma unroll
    for (int j = 0; j < 16; j++) acc[j] = 0.f;
    for (int m = 0; m < MM; m++) {
        float z = zern[m * PP + pix];
#pragma unroll
        for (int j = 0; j < 16; j++) acc[j] = fmaf(pl[j * MM + m], z, acc[j]);
    }
    float mk = mask[pix];
#pragma unroll
    for (int j = 0; j < 16; j++) phase[(size_t)(bg * 16 + j) * PP + pix] = acc[j] * mk;
}

// ---------------- stage 1: row DFTs (streamed radix-4 inner + 2x7 outer) -----
__global__ __launch_bounds__(256, 4) void k_stage1(const float* __restrict__ phase,
                                                   const float* __restrict__ mask,
                                                   unsigned* __restrict__ T) {
    __shared__ unsigned xs[16 * SX1];
    __shared__ unsigned ys[16 * SX1];
    int h0 = blockIdx.x * 16;
    int b = blockIdx.y, d = blockIdx.z;
    int t = threadIdx.x;

    const float* ph_base = phase + (size_t)b * PP + (size_t)h0 * PSZ;
    for (int idx = t; idx < 16 * PSZ; idx += 256) {
        int r = idx / PSZ, w = idx - r * PSZ;
        float ph = ph_base[r * PSZ + w];
        if (d) {
            float vy = lincoord(h0 + r), vx = lincoord(w);
            ph += DEFOCUS_RAD * (2.f * (vx * vx + vy * vy) - 1.f);
        }
        float mk = mask[(h0 + r) * PSZ + w];
        float sn, cs;
        fast_sincos(ph, &sn, &cs);
        xs[r * SX1 + w] = pack_bf2(mk * cs, mk * sn);
    }
    __syncthreads();

    if (t < 224) {                    // inner: 16 rows x 14 n1, xs -> ys
        int r = t / 14, n1 = t - r * 14;
        int a = r * SX1 + n1;
        inner224(xs, ys, a, a, 14, n1);
    }
    __syncthreads();

    {                                 // outer: 16 rows x 16 k2, ys -> T
        int r = t >> 4, k2 = t & 15;
        const unsigned* yb = ys + r * SX1 + k2 * 14;
        float2 y[14];
#pragma unroll
        for (int n = 0; n < 14; n++) y[n] = unpack_bf2(yb[n]);
        int img = d * BB + b;
        unsigned* Trow = T + ((size_t)img * PSZ + (h0 + r)) * PSZ;
        {   // k1 = 0
            float2 E = cadd(cadd(cadd(y[0], y[2]), cadd(y[4], y[6])),
                            cadd(cadd(y[8], y[10]), y[12]));
            float2 O = cadd(cadd(cadd(y[1], y[3]), cadd(y[5], y[7])),
                            cadd(cadd(y[9], y[11]), y[13]));
            float2 s = cadd(E, O), q = csub(E, O);
            Trow[k2]          = pack_bf2(s.x, s.y);
            Trow[16 * 7 + k2] = pack_bf2(q.x, q.y);
        }
#pragma unroll
        for (int k1 = 1; k1 < 7; k1++) {
            float2 E = y[0], O = y[1];
#pragma unroll
            for (int m = 1; m < 7; m++) {
                const float wr = W7R[(m * k1) % 7], wi = W7I[(m * k1) % 7];
                E.x = fmaf(y[2*m].x, wr, E.x);   E.x = fmaf(-y[2*m].y, wi, E.x);
                E.y = fmaf(y[2*m].x, wi, E.y);   E.y = fmaf(y[2*m].y, wr, E.y);
                O.x = fmaf(y[2*m+1].x, wr, O.x); O.x = fmaf(-y[2*m+1].y, wi, O.x);
                O.y = fmaf(y[2*m+1].x, wi, O.y); O.y = fmaf(y[2*m+1].y, wr, O.y);
            }
            float2 Op = cmulc(O, W14R[k1], W14I[k1]);
            float2 s = cadd(E, Op), q = csub(E, Op);
            Trow[16 * k1 + k2]       = pack_bf2(s.x, s.y);
            Trow[16 * (k1 + 7) + k2] = pack_bf2(q.x, q.y);
        }
    }
}

// ---------------- stage 2: column DFTs + psf + loss + atomic finale ----------
__global__ __launch_bounds__(256, 4) void k_stage2(const unsigned* __restrict__ T,
                                                   const float* __restrict__ psfs,
                                                   float* __restrict__ ws,
                                                   float* __restrict__ out) {
    __shared__ unsigned xs[224 * SX2];
    __shared__ unsigned ys[224 * SX2];
    __shared__ float red[256];
    int tile = blockIdx.x, b = blockIdx.y, d = blockIdx.z;
    int img = d * BB + b;
    int col0 = tile * 16;
    int t = threadIdx.x;

    const unsigned* Tbase = T + (size_t)img * PP + col0;
    for (int idx = t; idx < 224 * 16; idx += 256) {
        int h = idx >> 4, c = idx & 15;
        xs[h * SX2 + c] = Tbase[(size_t)h * PSZ + c];
    }
    __syncthreads();

    if (t < 224) {                    // inner: 14 n1 x 16 c, xs -> ys
        int n1 = t >> 4, c = t & 15;
        int a = n1 * SX2 + c;
        inner224(xs, ys, a, a, 14 * SX2, n1);
    }
    __syncthreads();

    float m2 = 0.f;
#pragma unroll
    for (int i = 0; i < 7; i++) m2 += ws[2 + i];       // uniform scalar loads
    float inv_denom = 1.f / (m2 * (float)PP + EPS_F);  // Parseval denominator

    {                                 // outer: 16 k2 x 16 c, ys -> psf (in xs, dead)
        int k2 = t >> 4, c = t & 15;
        float2 y[14];
#pragma unroll
        for (int n = 0; n < 14; n++) y[n] = unpack_bf2(ys[(k2 * 14 + n) * SX2 + c]);
        {   // k1 = 0
            float2 E = cadd(cadd(cadd(y[0], y[2]), cadd(y[4], y[6])),
                            cadd(cadd(y[8], y[10]), y[12]));
            float2 O = cadd(cadd(cadd(y[1], y[3]), cadd(y[5], y[7])),
                            cadd(cadd(y[9], y[11]), y[13]));
            float2 s = cadd(E, O), q = csub(E, O);
            xs[(k2)*SX2 + c] =
                __float_as_uint(fmaf(s.x, s.x, s.y * s.y) * inv_denom);
            xs[(16 * 7 + k2) * SX2 + c] =
                __float_as_uint(fmaf(q.x, q.x, q.y * q.y) * inv_denom);
        }
#pragma unroll
        for (int k1 = 1; k1 < 7; k1++) {
            float2 E = y[0], O = y[1];
#pragma unroll
            for (int m = 1; m < 7; m++) {
                const float wr = W7R[(m * k1) % 7], wi = W7I[(m * k1) % 7];
                E.x = fmaf(y[2*m].x, wr, E.x);   E.x = fmaf(-y[2*m].y, wi, E.x);
                E.y = fmaf(y[2*m].x, wi, E.y);   E.y = fmaf(y[2*m].y, wr, E.y);
                O.x = fmaf(y[2*m+1].x, wr, O.x); O.x = fmaf(-y[2*m+1].y, wi, O.x);
                O.y = fmaf(y[2*m+1].x, wi, O.y); O.y = fmaf(y[2*m+1].y, wr, O.y);
            }
            float2 Op = cmulc(O, W14R[k1], W14I[k1]);
            float2 s = cadd(E, Op), q = csub(E, Op);
            xs[(16 * k1 + k2) * SX2 + c] =
                __float_as_uint(fmaf(s.x, s.x, s.y * s.y) * inv_denom);
            xs[(16 * (k1 + 7) + k2) * SX2 + c] =
                __float_as_uint(fmaf(q.x, q.x, q.y * q.y) * inv_denom);
        }
    }
    __syncthreads();

    int scol0 = 16 * ((tile + 7) % 14);
    const float* inp = psfs + ((size_t)b * 2 + d) * PP;
    float lsum = 0.f;
    for (int idx = t; idx < 224 * 16; idx += 256) {
        int kh = idx >> 4, cc = idx & 15;
        int skh = kh + 112; if (skh >= 224) skh -= 224;
        float diff = __uint_as_float(xs[kh * SX2 + cc]) - inp[skh * PSZ + scol0 + cc];
        lsum = fmaf(diff, diff, lsum);
    }
    red[t] = lsum;
    __syncthreads();
    for (int st = 128; st > 0; st >>= 1) {
        if (t < st) red[t] += red[t + st];
        __syncthreads();
    }
    if (t == 0) {
        atomicAdd(&ws[10], red[0]);
        __threadfence();
        unsigned old = atomicAdd((unsigned*)ws + 11, 1u);
        if (old == NBLK2 - 1) {
            float total = atomicAdd(&ws[10], 0.f);
            float recon = total / (float)((size_t)BB * PP);
            out[0] = ws[1] + RECON_WEIGHT * recon;
        }
    }
}

extern "C" void kernel_launch(void* const* d_in, const int* in_sizes, int n_in,
                              void* d_out, int out_size, void* d_ws, size_t ws_size,
                              hipStream_t stream) {
    const float* pred   = (const float*)d_in[0];
    const float* target = (const float*)d_in[1];
    const float* psfs   = (const float*)d_in[2];
    const float* zern   = (const float*)d_in[3];
    const float* mask   = (const float*)d_in[4];

    float*    ws    = (float*)d_ws;
    float*    phase = ws + WS_PHASE_OFF;
    unsigned* T     = (unsigned*)(ws + WS_T_OFF);
    float*    out   = (float*)d_out;

    k_phase<<<dim3(197, 8), 256, 0, stream>>>(pred, target, zern, mask, phase, ws);
    k_stage1<<<dim3(14, BB, 2), 256, 0, stream>>>(phase, mask, T);
    k_stage2<<<dim3(14, BB, 2), 256, 0, stream>>>(T, psfs, ws, out);
}

// Round 8
// 199.210 us; speedup vs baseline: 1.5716x; 1.5716x over previous
//
#include <hip/hip_runtime.h>
#include <math.h>

#define BB 128
#define MM 35
#define PSZ 224
#define PP (PSZ*PSZ)          // 50176
#define SIGN_PENALTY 10.0f
#define RECON_WEIGHT 0.4f
#define DEFOCUS_RAD 1.0f
#define EPS_F 1e-8f
#define INV2PI 0.15915494309189535f

// CT: 224 = 14*16.  n = 14*n2 + n1; k = 16*k1 + k2.
// Thread n1 owns slots {14n2+n1} == {k2*14+n1} → in-place xs, bf16x2 packed.
// Inner 16-pt DFT: radix-2 DIF pre-pass (u/v into ys, self-owned slots, no
// barrier) + two direct 8-term DFTs — keeps R4's high-ILP direct-DFT shape.
// Outer 14-pt: sequential 2x7 (R4-proven). NO device atomics (R5-R7 lesson:
// same-address atomic finale serialized block retirement, ~+100 µs).

// ws layout (floats):
//   [1] z_loss  [2..8] mask^2 partials (7)
//   [2048 ..) phase [B][P][P] — dead after stage1; partials alias it
//   [T_OFF ..) T [2][B][P][P] packed bf16x2
#define WS_PHASE_OFF    2048
#define WS_T_OFF        (WS_PHASE_OFF + BB*PP)
#define N_PARTIALS      (14*BB*2)
#define S1 232            // stage1 LDS row stride (dwords)
#define S2 17             // stage2 LDS col-tile stride (dwords)

static constexpr float W16R[16] = {
    1.0f, 0.9238795325f, 0.7071067812f, 0.3826834324f, 0.0f,
    -0.3826834324f, -0.7071067812f, -0.9238795325f, -1.0f,
    -0.9238795325f, -0.7071067812f, -0.3826834324f, 0.0f,
    0.3826834324f, 0.7071067812f, 0.9238795325f};
static constexpr float W16I[16] = {
    0.0f, -0.3826834324f, -0.7071067812f, -0.9238795325f, -1.0f,
    -0.9238795325f, -0.7071067812f, -0.3826834324f, 0.0f,
    0.3826834324f, 0.7071067812f, 0.9238795325f, 1.0f,
    0.9238795325f, 0.7071067812f, 0.3826834324f};
static constexpr float W7R[7] = {
    1.0f, 0.6234898019f, -0.2225209340f, -0.9009688679f,
    -0.9009688679f, -0.2225209340f, 0.6234898019f};
static constexpr float W7I[7] = {
    0.0f, -0.7818314825f, -0.9749279122f, -0.4338837391f,
    0.4338837391f, 0.9749279122f, 0.7818314825f};
static constexpr float W14R[7] = {
    1.0f, 0.9009688679f, 0.6234898019f, 0.2225209340f, -0.2225209340f,
    -0.6234898019f, -0.9009688679f};
static constexpr float W14I[7] = {
    0.0f, -0.4338837391f, -0.7818314825f, -0.9749279122f, -0.9749279122f,
    -0.7818314825f, -0.4338837391f};

__device__ __forceinline__ float lincoord(int i) {
    return -1.0f + 2.0f * (float)i / (float)(PSZ - 1);
}
__device__ __forceinline__ void fast_sincos(float x, float* s, float* c) {
    float rv = x * INV2PI;
    rv -= floorf(rv);
    *s = __builtin_amdgcn_sinf(rv);
    *c = __builtin_amdgcn_cosf(rv);
}
// e^{-2*pi*i*frac}: returns (cos, sin)
__device__ __forceinline__ float2 wexp_neg(float frac) {
    float rv = -frac;
    rv -= floorf(rv);
    return make_float2(__builtin_amdgcn_cosf(rv), __builtin_amdgcn_sinf(rv));
}
__device__ __forceinline__ unsigned pack_bf2(float a, float b) {
    return ((__float_as_uint(a) + 0x8000u) >> 16) |
           ((__float_as_uint(b) + 0x8000u) & 0xffff0000u);
}
__device__ __forceinline__ float2 unpack_bf2(unsigned v) {
    return make_float2(__uint_as_float(v << 16), __uint_as_float(v & 0xffff0000u));
}
__device__ __forceinline__ float2 cmul(float2 a, float2 b) {
    return make_float2(fmaf(a.x, b.x, -a.y * b.y), fmaf(a.x, b.y, a.y * b.x));
}
__device__ __forceinline__ float2 cmulc(float2 a, float wr, float wi) {
    return make_float2(fmaf(a.x, wr, -a.y * wi), fmaf(a.x, wi, a.y * wr));
}
__device__ __forceinline__ float2 cadd(float2 a, float2 b) {
    return make_float2(a.x + b.x, a.y + b.y);
}
__device__ __forceinline__ float2 csub(float2 a, float2 b) {
    return make_float2(a.x - b.x, a.y - b.y);
}

// Inner 224-split stage: 16-pt DFT (radix-2 DIF) + W224^{n1*k2} twiddle.
// src/dst slots at base + (14*j+n1)*mul; u/v staging in ysrc (same layout).
// All touched slots are owned exclusively by this thread — no barrier needed.
__device__ __forceinline__ void inner16_dif(unsigned* __restrict__ xbuf,
                                            unsigned* __restrict__ ybuf,
                                            int base, int mul, int n1) {
    // phase A: u[n] = x[n]+x[n+8] -> ybuf slot n; v[n] = (x[n]-x[n+8])*W16^n -> slot n+8
#pragma unroll
    for (int n = 0; n < 8; n++) {
        float2 a = unpack_bf2(xbuf[base + (14 * n) * mul]);
        float2 b = unpack_bf2(xbuf[base + (14 * (n + 8)) * mul]);
        float2 u = cadd(a, b);
        float2 w = csub(a, b);
        float2 v = (n == 0) ? w : cmulc(w, W16R[n], W16I[n]);
        ybuf[base + (14 * n) * mul]       = pack_bf2(u.x, u.y);
        ybuf[base + (14 * (n + 8)) * mul] = pack_bf2(v.x, v.y);
    }
    float2 u1 = wexp_neg((float)n1 * (1.0f / 224.0f));   // W224^{n1}
    float2 u2 = wexp_neg((float)n1 * (1.0f / 112.0f));   // W224^{2*n1}
    // phase B even: X[2m] = sum_n u[n] * W8^{nm}, twiddle cur = u2^m
    {
        float2 u[8];
#pragma unroll
        for (int n = 0; n < 8; n++) u[n] = unpack_bf2(ybuf[base + (14 * n) * mul]);
        float2 cur = make_float2(1.f, 0.f);
#pragma unroll
        for (int m = 0; m < 8; m++) {
            float ar = u[0].x, ai = u[0].y;
#pragma unroll
            for (int n = 1; n < 8; n++) {
                const float wr = W16R[(2 * n * m) & 15], wi = W16I[(2 * n * m) & 15];
                ar = fmaf(u[n].x, wr, ar); ar = fmaf(-u[n].y, wi, ar);
                ai = fmaf(u[n].x, wi, ai); ai = fmaf(u[n].y, wr, ai);
            }
            float2 z = (m == 0) ? make_float2(ar, ai) : cmul(make_float2(ar, ai), cur);
            xbuf[base + (2 * m * 14) * mul] = pack_bf2(z.x, z.y);
            cur = cmul(cur, u2);
        }
    }
    // phase B odd: X[2m+1] = sum_n v[n] * W8^{nm}, twiddle cur = u1 * u2^m
    {
        float2 v[8];
#pragma unroll
        for (int n = 0; n < 8; n++) v[n] = unpack_bf2(ybuf[base + (14 * (n + 8)) * mul]);
        float2 cur = u1;
#pragma unroll
        for (int m = 0; m < 8; m++) {
            float ar = v[0].x, ai = v[0].y;
#pragma unroll
            for (int n = 1; n < 8; n++) {
                const float wr = W16R[(2 * n * m) & 15], wi = W16I[(2 * n * m) & 15];
                ar = fmaf(v[n].x, wr, ar); ar = fmaf(-v[n].y, wi, ar);
                ai = fmaf(v[n].x, wi, ai); ai = fmaf(v[n].y, wr, ai);
            }
            float2 z = cmul(make_float2(ar, ai), cur);
            xbuf[base + ((2 * m + 1) * 14) * mul] = pack_bf2(z.x, z.y);
            cur = cmul(cur, u2);
        }
    }
}

// ---------------- k_phase: grid (197, 8). x<196: phase GEMM. x==196: small work.
__global__ __launch_bounds__(256) void k_phase(const float* __restrict__ pred,
                                               const float* __restrict__ target,
                                               const float* __restrict__ zern,
                                               const float* __restrict__ mask,
                                               float* __restrict__ phase,
                                               float* __restrict__ ws) {
    __shared__ float pl[16 * MM];
    __shared__ float red[256];
    int t = threadIdx.x;
    if (blockIdx.x == 196) {
        int y = blockIdx.y;
        float s = 0.f;
        if (y == 0) {
            for (int i = t; i < BB * MM; i += 256) {
                float p = pred[i], tg = target[i];
                float dd = p - tg;
                float w = (p * tg < 0.f) ? SIGN_PENALTY : 1.f;
                s = fmaf(dd * dd, w, s);
            }
        } else {
            const float4* m4 = (const float4*)(mask + (y - 1) * (PP / 7));
            for (int i = t; i < PP / 28; i += 256) {
                float4 v = m4[i];
                s = fmaf(v.x, v.x, s); s = fmaf(v.y, v.y, s);
                s = fmaf(v.z, v.z, s); s = fmaf(v.w, v.w, s);
            }
        }
        red[t] = s;
        __syncthreads();
        for (int st = 128; st > 0; st >>= 1) {
            if (t < st) red[t] += red[t + st];
            __syncthreads();
        }
        if (t == 0) {
            if (y == 0) ws[1] = red[0] / (float)(BB * MM);
            else        ws[1 + y] = red[0];
        }
        return;
    }
    int bg = blockIdx.y;
    for (int i = t; i < 16 * MM; i += 256) {
        int j = i / MM, m = i % MM;
        pl[i] = pred[(bg * 16 + j) * MM + m];
    }
    __syncthreads();
    int pix = blockIdx.x * 256 + t;
    float acc[16];
#pragma unroll
    for (int j = 0; j < 16; j++) acc[j] = 0.f;
    for (int m = 0; m < MM; m++) {
        float z = zern[m * PP + pix];
#pragma unroll
        for (int j = 0; j < 16; j++) acc[j] = fmaf(pl[j * MM + m], z, acc[j]);
    }
    float mk = mask[pix];
#pragma unroll
    for (int j = 0; j < 16; j++) phase[(size_t)(bg * 16 + j) * PP + pix] = acc[j] * mk;
}

// ---------------- stage 1: row DFTs (DIF inner + 2x7 outer), bf16 ------------
__global__ __launch_bounds__(256, 4) void k_stage1(const float* __restrict__ phase,
                                                   const float* __restrict__ mask,
                                                   unsigned* __restrict__ T) {
    __shared__ unsigned xs[16 * S1];
    __shared__ unsigned ys[16 * S1];
    int h0 = blockIdx.x * 16;
    int b = blockIdx.y, d = blockIdx.z;
    int t = threadIdx.x;

    const float* ph_base = phase + (size_t)b * PP + (size_t)h0 * PSZ;
    for (int idx = t; idx < 16 * PSZ; idx += 256) {
        int r = idx / PSZ, w = idx - r * PSZ;
        float ph = ph_base[r * PSZ + w];
        if (d) {
            float vy = lincoord(h0 + r), vx = lincoord(w);
            ph += DEFOCUS_RAD * (2.f * (vx * vx + vy * vy) - 1.f);
        }
        float mk = mask[(h0 + r) * PSZ + w];
        float sn, cs;
        fast_sincos(ph, &sn, &cs);
        xs[r * S1 + w] = pack_bf2(mk * cs, mk * sn);
    }
    __syncthreads();

    if (t < 224) {                    // inner: 16 rows x 14 n1, in-place xs (ys staging)
        int r = t / 14, n1 = t - r * 14;
        inner16_dif(xs, ys, r * S1 + n1, 1, n1);
    }
    __syncthreads();

    {                                 // outer: 16 rows x 16 k2, sequential 2x7
        int r = t >> 4, k2 = t & 15;
        const unsigned* xr = xs + r * S1;
        int img = d * BB + b;
        unsigned* Trow = T + ((size_t)img * PSZ + (h0 + r)) * PSZ;
        float2 e[7], E[7], O[7];
#pragma unroll
        for (int n = 0; n < 7; n++) e[n] = unpack_bf2(xr[k2 * 14 + 2 * n]);
#pragma unroll
        for (int k = 0; k < 7; k++) {
            float ar = e[0].x, ai = e[0].y;
#pragma unroll
            for (int n = 1; n < 7; n++) {
                const float wr = W7R[(n * k) % 7], wi = W7I[(n * k) % 7];
                ar = fmaf(e[n].x, wr, ar); ar = fmaf(-e[n].y, wi, ar);
                ai = fmaf(e[n].x, wi, ai); ai = fmaf(e[n].y, wr, ai);
            }
            E[k] = make_float2(ar, ai);
        }
#pragma unroll
        for (int n = 0; n < 7; n++) e[n] = unpack_bf2(xr[k2 * 14 + 2 * n + 1]);
#pragma unroll
        for (int k = 0; k < 7; k++) {
            float ar = e[0].x, ai = e[0].y;
#pragma unroll
            for (int n = 1; n < 7; n++) {
                const float wr = W7R[(n * k) % 7], wi = W7I[(n * k) % 7];
                ar = fmaf(e[n].x, wr, ar); ar = fmaf(-e[n].y, wi, ar);
                ai = fmaf(e[n].x, wi, ai); ai = fmaf(e[n].y, wr, ai);
            }
            O[k] = make_float2(ar, ai);
        }
#pragma unroll
        for (int k1 = 0; k1 < 7; k1++) {
            float2 op = (k1 == 0) ? O[0] : cmulc(O[k1], W14R[k1], W14I[k1]);
            float2 s = cadd(E[k1], op), q = csub(E[k1], op);
            Trow[16 * k1 + k2]       = pack_bf2(s.x, s.y);
            Trow[16 * (k1 + 7) + k2] = pack_bf2(q.x, q.y);
        }
    }
}

// ---------------- stage 2: column DFTs + psf + loss -> partials --------------
__global__ __launch_bounds__(256, 4) void k_stage2(const unsigned* __restrict__ T,
                                                   const float* __restrict__ psfs,
                                                   const float* __restrict__ ws,
                                                   float* __restrict__ partials) {
    __shared__ unsigned xs[224 * S2];
    __shared__ unsigned ys[224 * S2];
    __shared__ float red[256];
    int tile = blockIdx.x, b = blockIdx.y, d = blockIdx.z;
    int img = d * BB + b;
    int col0 = tile * 16;
    int t = threadIdx.x;

    const unsigned* Tbase = T + (size_t)img * PP + col0;
    for (int idx = t; idx < 224 * 16; idx += 256) {
        int h = idx >> 4, c = idx & 15;
        xs[h * S2 + c] = Tbase[(size_t)h * PSZ + c];
    }
    __syncthreads();

    if (t < 224) {                    // inner: 14 n1 x 16 c, in-place xs (ys staging)
        int n1 = t >> 4, c = t & 15;
        inner16_dif(xs, ys, n1 * S2 + c, S2, n1);
    }
    __syncthreads();

    float m2 = 0.f;
#pragma unroll
    for (int i = 0; i < 7; i++) m2 += ws[2 + i];       // uniform scalar loads
    float inv_denom = 1.f / (m2 * (float)PP + EPS_F);  // Parseval denominator

    {                                 // outer: 16 k2 x 16 c, 2x7; psf overwrites xs
        int k2 = t >> 4, c = t & 15;
        float2 e[7], E[7], O[7];
#pragma unroll
        for (int n = 0; n < 7; n++) e[n] = unpack_bf2(xs[(k2 * 14 + 2 * n) * S2 + c]);
#pragma unroll
        for (int k = 0; k < 7; k++) {
            float ar = e[0].x, ai = e[0].y;
#pragma unroll
            for (int n = 1; n < 7; n++) {
                const float wr = W7R[(n * k) % 7], wi = W7I[(n * k) % 7];
                ar = fmaf(e[n].x, wr, ar); ar = fmaf(-e[n].y, wi, ar);
                ai = fmaf(e[n].x, wi, ai); ai = fmaf(e[n].y, wr, ai);
            }
            E[k] = make_float2(ar, ai);
        }
#pragma unroll
        for (int n = 0; n < 7; n++) e[n] = unpack_bf2(xs[(k2 * 14 + 2 * n + 1) * S2 + c]);
#pragma unroll
        for (int k = 0; k < 7; k++) {
            float ar = e[0].x, ai = e[0].y;
#pragma unroll
            for (int n = 1; n < 7; n++) {
                const float wr = W7R[(n * k) % 7], wi = W7I[(n * k) % 7];
                ar = fmaf(e[n].x, wr, ar); ar = fmaf(-e[n].y, wi, ar);
                ai = fmaf(e[n].x, wi, ai); ai = fmaf(e[n].y, wr, ai);
            }
            O[k] = make_float2(ar, ai);
        }
        __syncthreads();   // all LDS reads done before psf writes clobber xs
#pragma unroll
        for (int k1 = 0; k1 < 7; k1++) {
            float2 op = (k1 == 0) ? O[0] : cmulc(O[k1], W14R[k1], W14I[k1]);
            float2 s = cadd(E[k1], op), q = csub(E[k1], op);
            xs[(16 * k1 + k2) * S2 + c] =
                __float_as_uint(fmaf(s.x, s.x, s.y * s.y) * inv_denom);
            xs[(16 * (k1 + 7) + k2) * S2 + c] =
                __float_as_uint(fmaf(q.x, q.x, q.y * q.y) * inv_denom);
        }
    }
    __syncthreads();

    int scol0 = 16 * ((tile + 7) % 14);
    const float* inp = psfs + ((size_t)b * 2 + d) * PP;
    float lsum = 0.f;
    for (int idx = t; idx < 224 * 16; idx += 256) {
        int kh = idx >> 4, cc = idx & 15;
        int skh = kh + 112; if (skh >= 224) skh -= 224;
        float diff = __uint_as_float(xs[kh * S2 + cc]) - inp[skh * PSZ + scol0 + cc];
        lsum = fmaf(diff, diff, lsum);
    }
    red[t] = lsum;
    __syncthreads();
    for (int st = 128; st > 0; st >>= 1) {
        if (t < st) red[t] += red[t + st];
        __syncthreads();
    }
    if (t == 0)
        partials[(blockIdx.z * BB + blockIdx.y) * 14 + blockIdx.x] = red[0];
}

// ---------------- final ----------------
__global__ void k_final(const float* __restrict__ ws,
                        const float* __restrict__ partials,
                        float* __restrict__ out) {
    __shared__ float red[256];
    float s = 0.f;
    for (int i = threadIdx.x; i < N_PARTIALS; i += 256) s += partials[i];
    red[threadIdx.x] = s;
    __syncthreads();
    for (int st = 128; st > 0; st >>= 1) {
        if (threadIdx.x < st) red[threadIdx.x] += red[threadIdx.x + st];
        __syncthreads();
    }
    if (threadIdx.x == 0) {
        float recon = red[0] / (float)((size_t)BB * PP);
        out[0] = ws[1] + RECON_WEIGHT * recon;
    }
}

extern "C" void kernel_launch(void* const* d_in, const int* in_sizes, int n_in,
                              void* d_out, int out_size, void* d_ws, size_t ws_size,
                              hipStream_t stream) {
    const float* pred   = (const float*)d_in[0];
    const float* target = (const float*)d_in[1];
    const float* psfs   = (const float*)d_in[2];
    const float* zern   = (const float*)d_in[3];
    const float* mask   = (const float*)d_in[4];

    float*    ws       = (float*)d_ws;
    float*    phase    = ws + WS_PHASE_OFF;
    float*    partials = ws + WS_PHASE_OFF;   // aliases phase (dead after stage1)
    unsigned* T        = (unsigned*)(ws + WS_T_OFF);
    float*    out      = (float*)d_out;

    k_phase<<<dim3(197, 8), 256, 0, stream>>>(pred, target, zern, mask, phase, ws);
    k_stage1<<<dim3(14, BB, 2), 256, 0, stream>>>(phase, mask, T);
    k_stage2<<<dim3(14, BB, 2), 256, 0, stream>>>(T, psfs, ws, partials);
    k_final<<<1, 256, 0, stream>>>(ws, partials, out);
}

// Round 9
// 197.942 us; speedup vs baseline: 1.5817x; 1.0064x over previous
//
#include <hip/hip_runtime.h>
#include <math.h>

#define BB 128
#define MM 35
#define PSZ 224
#define PP (PSZ*PSZ)          // 50176
#define SIGN_PENALTY 10.0f
#define RECON_WEIGHT 0.4f
#define DEFOCUS_RAD 1.0f
#define EPS_F 1e-8f
#define INV2PI 0.15915494309189535f

// CT: 224 = 14*16.  n = 14*n2 + n1; k = 16*k1 + k2.
// Thread n1 owns slots {14n2+n1} == {k2*14+n1} → in-place xs, bf16x2 packed.
// All small DFTs use conjugate-symmetry pair factorization:
//   a_n = x[n]+x[N-n], b_n = x[n]-x[N-n]; outputs (k, N-k) share P=Σc·a, Q=Σs·b.
// No ys staging (u/v in regs, evens written back before odd DFT → ~40 live floats).
// NO device atomics (R5-R7: 3584 same-address RMW+fence cost ~120 µs).

// ws layout (floats):
//   [1] z_loss  [2..4] mask^2 partials (3)
//   [2048 ..) phase [B][P][P] — dead after stage1; partials alias it
//   [T_OFF ..) T [2][B][P][P] packed bf16x2
#define WS_PHASE_OFF    2048
#define WS_T_OFF        (WS_PHASE_OFF + BB*PP)
#define N_PARTIALS      (14*BB*2)
#define S1 232            // stage1 LDS row stride (dwords)
#define S2 17             // stage2 LDS col-tile stride (dwords)

static constexpr float W16R[16] = {
    1.0f, 0.9238795325f, 0.7071067812f, 0.3826834324f, 0.0f,
    -0.3826834324f, -0.7071067812f, -0.9238795325f, -1.0f,
    -0.9238795325f, -0.7071067812f, -0.3826834324f, 0.0f,
    0.3826834324f, 0.7071067812f, 0.9238795325f};
static constexpr float W16I[16] = {
    0.0f, -0.3826834324f, -0.7071067812f, -0.9238795325f, -1.0f,
    -0.9238795325f, -0.7071067812f, -0.3826834324f, 0.0f,
    0.3826834324f, 0.7071067812f, 0.9238795325f, 1.0f,
    0.9238795325f, 0.7071067812f, 0.3826834324f};
static constexpr float W7R[7] = {
    1.0f, 0.6234898019f, -0.2225209340f, -0.9009688679f,
    -0.9009688679f, -0.2225209340f, 0.6234898019f};
static constexpr float W7I[7] = {
    0.0f, -0.7818314825f, -0.9749279122f, -0.4338837391f,
    0.4338837391f, 0.9749279122f, 0.7818314825f};
static constexpr float W14R[7] = {
    1.0f, 0.9009688679f, 0.6234898019f, 0.2225209340f, -0.2225209340f,
    -0.6234898019f, -0.9009688679f};
static constexpr float W14I[7] = {
    0.0f, -0.4338837391f, -0.7818314825f, -0.9749279122f, -0.9749279122f,
    -0.7818314825f, -0.4338837391f};

__device__ __forceinline__ float lincoord(int i) {
    return -1.0f + 2.0f * (float)i / (float)(PSZ - 1);
}
__device__ __forceinline__ void fast_sincos(float x, float* s, float* c) {
    float rv = x * INV2PI;
    rv -= floorf(rv);
    *s = __builtin_amdgcn_sinf(rv);
    *c = __builtin_amdgcn_cosf(rv);
}
// e^{-2*pi*i*frac}: returns (cos, sin)
__device__ __forceinline__ float2 wexp_neg(float frac) {
    float rv = -frac;
    rv -= floorf(rv);
    return make_float2(__builtin_amdgcn_cosf(rv), __builtin_amdgcn_sinf(rv));
}
__device__ __forceinline__ unsigned pack_bf2(float a, float b) {
    return ((__float_as_uint(a) + 0x8000u) >> 16) |
           ((__float_as_uint(b) + 0x8000u) & 0xffff0000u);
}
__device__ __forceinline__ float2 unpack_bf2(unsigned v) {
    return make_float2(__uint_as_float(v << 16), __uint_as_float(v & 0xffff0000u));
}
__device__ __forceinline__ float2 cmul(float2 a, float2 b) {
    return make_float2(fmaf(a.x, b.x, -a.y * b.y), fmaf(a.x, b.y, a.y * b.x));
}
__device__ __forceinline__ float2 cmulc(float2 a, float wr, float wi) {
    return make_float2(fmaf(a.x, wr, -a.y * wi), fmaf(a.x, wi, a.y * wr));
}
__device__ __forceinline__ float2 cadd(float2 a, float2 b) {
    return make_float2(a.x + b.x, a.y + b.y);
}
__device__ __forceinline__ float2 csub(float2 a, float2 b) {
    return make_float2(a.x - b.x, a.y - b.y);
}
// guarded FMA: c is always a compile-time constant -> branches fold
__device__ __forceinline__ void cfma(float& acc, float c, float v) {
    if (c == 0.f) return;
    if (c == 1.f)  { acc += v; return; }
    if (c == -1.f) { acc -= v; return; }
    acc = fmaf(c, v, acc);
}

// 8-pt forward DFT via conjugate-symmetric pairs. ~60 ops.
__device__ __forceinline__ void dft8_sym(const float2* u, float2* X) {
    float2 a1 = cadd(u[1], u[7]), b1 = csub(u[1], u[7]);
    float2 a2 = cadd(u[2], u[6]), b2 = csub(u[2], u[6]);
    float2 a3 = cadd(u[3], u[5]), b3 = csub(u[3], u[5]);
    float2 s04 = cadd(u[0], u[4]), d04 = csub(u[0], u[4]);
    X[0] = cadd(cadd(s04, a1), cadd(a2, a3));
    X[4] = cadd(csub(s04, a1), csub(a2, a3));
    {   // m=2/6: W8^{2n} = (-i)^n
        float2 p = csub(s04, a2);
        float2 q = csub(b1, b3);
        X[2] = make_float2(p.x + q.y, p.y - q.x);
        X[6] = make_float2(p.x - q.y, p.y + q.x);
    }
#pragma unroll
    for (int m = 1; m <= 3; m += 2) {   // m=1/7, m=3/5 (odd m: base = u0-u4)
        float Px = d04.x, Py = d04.y, Qx = 0.f, Qy = 0.f;
#pragma unroll
        for (int n = 1; n <= 3; n++) {
            const float cR = W16R[(2 * n * m) & 15], cI = W16I[(2 * n * m) & 15];
            const float2 a = (n == 1) ? a1 : (n == 2) ? a2 : a3;
            const float2 b = (n == 1) ? b1 : (n == 2) ? b2 : b3;
            cfma(Px, cR, a.x); cfma(Py, cR, a.y);
            cfma(Qx, cI, b.x); cfma(Qy, cI, b.y);
        }
        X[m]     = make_float2(Px - Qy, Py + Qx);
        X[8 - m] = make_float2(Px + Qy, Py - Qx);
    }
}

// 7-pt forward DFT via conjugate-symmetric pairs. ~50 ops.
__device__ __forceinline__ void dft7_sym(const float2* x, float2* X) {
    float2 a1 = cadd(x[1], x[6]), b1 = csub(x[1], x[6]);
    float2 a2 = cadd(x[2], x[5]), b2 = csub(x[2], x[5]);
    float2 a3 = cadd(x[3], x[4]), b3 = csub(x[3], x[4]);
    X[0] = cadd(cadd(x[0], a1), cadd(a2, a3));
#pragma unroll
    for (int k = 1; k <= 3; k++) {
        float Px = x[0].x, Py = x[0].y, Qx = 0.f, Qy = 0.f;
#pragma unroll
        for (int n = 1; n <= 3; n++) {
            const float cR = W7R[(n * k) % 7], cI = W7I[(n * k) % 7];
            const float2 a = (n == 1) ? a1 : (n == 2) ? a2 : a3;
            const float2 b = (n == 1) ? b1 : (n == 2) ? b2 : b3;
            cfma(Px, cR, a.x); cfma(Py, cR, a.y);
            cfma(Qx, cI, b.x); cfma(Qy, cI, b.y);
        }
        X[k]     = make_float2(Px - Qy, Py + Qx);
        X[7 - k] = make_float2(Px + Qy, Py - Qx);
    }
}

// Inner 224-split: 16-pt DFT (radix-2 + sym-8) + W224^{n1*k} twiddle, in-place.
// Slot k at xbuf[base + 14*k*mul]; all slots owned by this thread.
__device__ __forceinline__ void inner16_sym(unsigned* __restrict__ xbuf,
                                            int base, int mul, int n1) {
    float2 x[16];
#pragma unroll
    for (int n = 0; n < 16; n++) x[n] = unpack_bf2(xbuf[base + (14 * n) * mul]);
    float2 u[8], v[8];
#pragma unroll
    for (int n = 0; n < 8; n++) {
        u[n] = cadd(x[n], x[n + 8]);
        float2 w = csub(x[n], x[n + 8]);
        v[n] = (n == 0) ? w : cmulc(w, W16R[n], W16I[n]);
    }
    float2 u1w = wexp_neg((float)n1 * (1.0f / 224.0f));   // W224^{n1}
    float2 u2w = wexp_neg((float)n1 * (1.0f / 112.0f));   // W224^{2 n1}
    {   // even outputs X16[2m] = Xe[m] * u2^m — written before odd DFT (liveness)
        float2 Xe[8];
        dft8_sym(u, Xe);
        float2 cur = make_float2(1.f, 0.f);
#pragma unroll
        for (int m = 0; m < 8; m++) {
            float2 z = (m == 0) ? Xe[0] : cmul(Xe[m], cur);
            xbuf[base + (14 * (2 * m)) * mul] = pack_bf2(z.x, z.y);
            cur = cmul(cur, u2w);
        }
    }
    {   // odd outputs X16[2m+1] = Xo[m] * u1 * u2^m
        float2 Xo[8];
        dft8_sym(v, Xo);
        float2 cur = u1w;
#pragma unroll
        for (int m = 0; m < 8; m++) {
            float2 z = cmul(Xo[m], cur);
            xbuf[base + (14 * (2 * m + 1)) * mul] = pack_bf2(z.x, z.y);
            cur = cmul(cur, u2w);
        }
    }
}

// ---------------- k_phase: grid (197, 4). x<196: phase GEMM (32 b each).
// x==196: y0 zloss, y1..3 mask^2 thirds.
__global__ __launch_bounds__(256) void k_phase(const float* __restrict__ pred,
                                               const float* __restrict__ target,
                                               const float* __restrict__ zern,
                                               const float* __restrict__ mask,
                                               float* __restrict__ phase,
                                               float* __restrict__ ws) {
    __shared__ float pl[32 * MM];
    __shared__ float red[256];
    int t = threadIdx.x;
    if (blockIdx.x == 196) {
        int y = blockIdx.y;
        float s = 0.f;
        if (y == 0) {
            for (int i = t; i < BB * MM; i += 256) {
                float p = pred[i], tg = target[i];
                float dd = p - tg;
                float w = (p * tg < 0.f) ? SIGN_PENALTY : 1.f;
                s = fmaf(dd * dd, w, s);
            }
        } else {
            const int F4 = PP / 4;                 // 12544 float4s
            int st = (y - 1) * 4182;
            int en = (y == 3) ? F4 : st + 4182;
            const float4* m4 = (const float4*)mask;
            for (int i = st + t; i < en; i += 256) {
                float4 v = m4[i];
                s = fmaf(v.x, v.x, s); s = fmaf(v.y, v.y, s);
                s = fmaf(v.z, v.z, s); s = fmaf(v.w, v.w, s);
            }
        }
        red[t] = s;
        __syncthreads();
        for (int st = 128; st > 0; st >>= 1) {
            if (t < st) red[t] += red[t + st];
            __syncthreads();
        }
        if (t == 0) {
            if (y == 0) ws[1] = red[0] / (float)(BB * MM);
            else        ws[1 + y] = red[0];        // ws[2..4]
        }
        return;
    }
    int bg = blockIdx.y;
    for (int i = t; i < 32 * MM; i += 256) {
        int j = i / MM, m = i % MM;
        pl[i] = pred[(bg * 32 + j) * MM + m];
    }
    __syncthreads();
    int pix = blockIdx.x * 256 + t;
    float acc[32];
#pragma unroll
    for (int j = 0; j < 32; j++) acc[j] = 0.f;
    for (int m = 0; m < MM; m++) {
        float z = zern[m * PP + pix];
#pragma unroll
        for (int j = 0; j < 32; j++) acc[j] = fmaf(pl[j * MM + m], z, acc[j]);
    }
    float mk = mask[pix];
#pragma unroll
    for (int j = 0; j < 32; j++) phase[(size_t)(bg * 32 + j) * PP + pix] = acc[j] * mk;
}

// ---------------- stage 1: row DFTs (sym inner + sym 2x7 outer), bf16 --------
__global__ __launch_bounds__(256, 6) void k_stage1(const float* __restrict__ phase,
                                                   const float* __restrict__ mask,
                                                   unsigned* __restrict__ T) {
    __shared__ unsigned xs[16 * S1];
    int h0 = blockIdx.x * 16;
    int b = blockIdx.y, d = blockIdx.z;
    int t = threadIdx.x;

    const float* ph_base = phase + (size_t)b * PP + (size_t)h0 * PSZ;
    for (int idx = t; idx < 16 * PSZ; idx += 256) {
        int r = idx / PSZ, w = idx - r * PSZ;
        float ph = ph_base[r * PSZ + w];
        if (d) {
            float vy = lincoord(h0 + r), vx = lincoord(w);
            ph += DEFOCUS_RAD * (2.f * (vx * vx + vy * vy) - 1.f);
        }
        float mk = mask[(h0 + r) * PSZ + w];
        float sn, cs;
        fast_sincos(ph, &sn, &cs);
        xs[r * S1 + w] = pack_bf2(mk * cs, mk * sn);
    }
    __syncthreads();

    if (t < 224) {                    // inner: 16 rows x 14 n1, in-place
        int r = t / 14, n1 = t - r * 14;
        inner16_sym(xs, r * S1 + n1, 1, n1);
    }
    __syncthreads();

    {                                 // outer: 16 rows x 16 k2, sym 2x7
        int r = t >> 4, k2 = t & 15;
        const unsigned* xr = xs + r * S1 + k2 * 14;
        int img = d * BB + b;
        unsigned* Trow = T + ((size_t)img * PSZ + (h0 + r)) * PSZ;
        float2 e[7], E[7], O[7];
#pragma unroll
        for (int n = 0; n < 7; n++) e[n] = unpack_bf2(xr[2 * n]);
        dft7_sym(e, E);
#pragma unroll
        for (int n = 0; n < 7; n++) e[n] = unpack_bf2(xr[2 * n + 1]);
        dft7_sym(e, O);
#pragma unroll
        for (int k1 = 0; k1 < 7; k1++) {
            float2 op = (k1 == 0) ? O[0] : cmulc(O[k1], W14R[k1], W14I[k1]);
            float2 s = cadd(E[k1], op), q = csub(E[k1], op);
            Trow[16 * k1 + k2]       = pack_bf2(s.x, s.y);
            Trow[16 * (k1 + 7) + k2] = pack_bf2(q.x, q.y);
        }
    }
}

// ---------------- stage 2: column DFTs + psf + loss -> partials --------------
__global__ __launch_bounds__(256, 6) void k_stage2(const unsigned* __restrict__ T,
                                                   const float* __restrict__ psfs,
                                                   const float* __restrict__ ws,
                                                   float* __restrict__ partials) {
    __shared__ unsigned xs[224 * S2];
    __shared__ float red[256];
    int tile = blockIdx.x, b = blockIdx.y, d = blockIdx.z;
    int img = d * BB + b;
    int col0 = tile * 16;
    int t = threadIdx.x;

    const unsigned* Tbase = T + (size_t)img * PP + col0;
    for (int idx = t; idx < 224 * 16; idx += 256) {
        int h = idx >> 4, c = idx & 15;
        xs[h * S2 + c] = Tbase[(size_t)h * PSZ + c];
    }
    __syncthreads();

    if (t < 224) {                    // inner: 14 n1 x 16 c, in-place
        int n1 = t >> 4, c = t & 15;
        inner16_sym(xs, n1 * S2 + c, S2, n1);
    }
    __syncthreads();

    float m2 = ws[2] + ws[3] + ws[4];                  // uniform scalar loads
    float inv_denom = 1.f / (m2 * (float)PP + EPS_F);  // Parseval denominator

    {                                 // outer: 16 k2 x 16 c; psf overwrites xs
        int k2 = t >> 4, c = t & 15;
        float2 e[7], E[7], O[7];
#pragma unroll
        for (int n = 0; n < 7; n++) e[n] = unpack_bf2(xs[(k2 * 14 + 2 * n) * S2 + c]);
        dft7_sym(e, E);
#pragma unroll
        for (int n = 0; n < 7; n++) e[n] = unpack_bf2(xs[(k2 * 14 + 2 * n + 1) * S2 + c]);
        dft7_sym(e, O);
        __syncthreads();   // all LDS reads done before psf writes clobber xs
#pragma unroll
        for (int k1 = 0; k1 < 7; k1++) {
            float2 op = (k1 == 0) ? O[0] : cmulc(O[k1], W14R[k1], W14I[k1]);
            float2 s = cadd(E[k1], op), q = csub(E[k1], op);
            xs[(16 * k1 + k2) * S2 + c] =
                __float_as_uint(fmaf(s.x, s.x, s.y * s.y) * inv_denom);
            xs[(16 * (k1 + 7) + k2) * S2 + c] =
                __float_as_uint(fmaf(q.x, q.x, q.y * q.y) * inv_denom);
        }
    }
    __syncthreads();

    int scol0 = 16 * ((tile + 7) % 14);
    const float* inp = psfs + ((size_t)b * 2 + d) * PP;
    float lsum = 0.f;
    for (int idx = t; idx < 224 * 16; idx += 256) {
        int kh = idx >> 4, cc = idx & 15;
        int skh = kh + 112; if (skh >= 224) skh -= 224;
        float diff = __uint_as_float(xs[kh * S2 + cc]) - inp[skh * PSZ + scol0 + cc];
        lsum = fmaf(diff, diff, lsum);
    }
    red[t] = lsum;
    __syncthreads();
    for (int st = 128; st > 0; st >>= 1) {
        if (t < st) red[t] += red[t + st];
        __syncthreads();
    }
    if (t == 0)
        partials[(blockIdx.z * BB + blockIdx.y) * 14 + blockIdx.x] = red[0];
}

// ---------------- final ----------------
__global__ void k_final(const float* __restrict__ ws,
                        const float* __restrict__ partials,
                        float* __restrict__ out) {
    __shared__ float red[256];
    float s = 0.f;
    for (int i = threadIdx.x; i < N_PARTIALS; i += 256) s += partials[i];
    red[threadIdx.x] = s;
    __syncthreads();
    for (int st = 128; st > 0; st >>= 1) {
        if (threadIdx.x < st) red[threadIdx.x] += red[threadIdx.x + st];
        __syncthreads();
    }
    if (threadIdx.x == 0) {
        float recon = red[0] / (float)((size_t)BB * PP);
        out[0] = ws[1] + RECON_WEIGHT * recon;
    }
}

extern "C" void kernel_launch(void* const* d_in, const int* in_sizes, int n_in,
                              void* d_out, int out_size, void* d_ws, size_t ws_size,
                              hipStream_t stream) {
    const float* pred   = (const float*)d_in[0];
    const float* target = (const float*)d_in[1];
    const float* psfs   = (const float*)d_in[2];
    const float* zern   = (const float*)d_in[3];
    const float* mask   = (const float*)d_in[4];

    float*    ws       = (float*)d_ws;
    float*    phase    = ws + WS_PHASE_OFF;
    float*    partials = ws + WS_PHASE_OFF;   // aliases phase (dead after stage1)
    unsigned* T        = (unsigned*)(ws + WS_T_OFF);
    float*    out      = (float*)d_out;

    k_phase<<<dim3(197, 4), 256, 0, stream>>>(pred, target, zern, mask, phase, ws);
    k_stage1<<<dim3(14, BB, 2), 256, 0, stream>>>(phase, mask, T);
    k_stage2<<<dim3(14, BB, 2), 256, 0, stream>>>(T, psfs, ws, partials);
    k_final<<<1, 256, 0, stream>>>(ws, partials, out);
}